// Round 2
// baseline (268.580 us; speedup 1.0000x reference)
//
#include <hip/hip_runtime.h>

// 3x3 VALID conv, NCHW fp32: data [16,64,128,128], weights [128,64,3,3]
// -> out [16,128,126,126].
// v2: NHWC-bf16 pre-transpose + halo-staged implicit-GEMM MFMA.
//   - halo (10h x 34w x 64ci, pixel rows padded to 72 shorts) staged ONCE/block
//   - weights [tap][co][ci] double-buffered via global_load_lds (async prefetch)
//   - block tile 128co x 256 spatial (8h x 32w), 4 waves, acc 4x8 f32x4/wave

#define BATCH 16
#define CIN   64
#define HIN   128
#define WIN   128
#define COUT  128
#define HO    126
#define WO    126

#define HROW 10   // halo rows
#define HPIX 34   // halo pixels per row
#define CPAD 72   // shorts per halo pixel (64 + 8 pad -> 144B stride, 2-way free)

typedef short bf16x8 __attribute__((ext_vector_type(8)));
typedef float f32x4  __attribute__((ext_vector_type(4)));
typedef unsigned short u16x8 __attribute__((ext_vector_type(8)));

__device__ __forceinline__ unsigned short f2bf(float f) {
    union { float f; unsigned int u; } v; v.f = f;
    unsigned int u = v.u;
    return (unsigned short)((u + 0x7fffu + ((u >> 16) & 1u)) >> 16);
}

// async global->LDS, 16B/lane. LDS dest must be wave-uniform base + lane*16.
__device__ __forceinline__ void async16(const void* g, void* l) {
    __builtin_amdgcn_global_load_lds(
        (const __attribute__((address_space(1))) unsigned int*)(unsigned long long)g,
        (__attribute__((address_space(3))) unsigned int*)(unsigned long long)l,
        16, 0, 0);
}

// ---------- Pre-pass 1: NCHW fp32 -> NHWC bf16 ----------
// grid (128 h, 16 b), block 256. Block handles one (b,h): 64ci x 128w.
__global__ __launch_bounds__(256) void t1_nchw_to_nhwc(
        const float* __restrict__ x, unsigned short* __restrict__ y) {
    __shared__ unsigned short tile[64 * 132]; // [ci][w], row 132 shorts (264B)
    const int h = blockIdx.x, b = blockIdx.y;
    const int t = threadIdx.x;

    const float* src = x + ((size_t)b * CIN) * (HIN * WIN) + h * WIN;
#pragma unroll
    for (int i = 0; i < 8; i++) {
        const int idx = t + i * 256;
        const int ci = idx >> 5, w4 = (idx & 31) * 4;
        float4 v = *(const float4*)(src + (size_t)ci * (HIN * WIN) + w4);
        ushort4 u = { f2bf(v.x), f2bf(v.y), f2bf(v.z), f2bf(v.w) };
        *(ushort4*)&tile[ci * 132 + w4] = u; // b64, 2-way free
    }
    __syncthreads();

    unsigned short* dst = y + (((size_t)b * HIN + h) * WIN) * CIN;
#pragma unroll
    for (int i = 0; i < 4; i++) {
        const int idx = t + i * 256;
        const int w = idx >> 3, c8 = (idx & 7) * 8;
        u16x8 u;
#pragma unroll
        for (int j = 0; j < 8; j++)
            u[j] = tile[(c8 + j) * 132 + w];
        *(u16x8*)&dst[(size_t)w * CIN + c8] = u; // 128B/8lanes coalesced
    }
}

// ---------- Pre-pass 2: weights [co][ci][3][3] fp32 -> [tap][co][ci] bf16 ----------
__global__ __launch_bounds__(256) void t2_weights(
        const float* __restrict__ w, unsigned short* __restrict__ wt) {
    const int idx = blockIdx.x * 256 + threadIdx.x;
    if (idx < COUT * CIN * 9) {
        const int co = idx / (CIN * 9);
        const int r  = idx % (CIN * 9);
        const int ci = r / 9;
        const int k  = r % 9;
        wt[((size_t)k * COUT + co) * CIN + ci] = f2bf(w[idx]);
    }
}

// ---------- Main: halo-staged implicit-GEMM MFMA conv ----------
// grid (4 wtiles, 16 htiles, 16 b) = 1024 blocks, 256 threads (4 waves).
// Block tile: 128co x (8h x 32w). K = 9 taps x 64 ci.
__global__ __launch_bounds__(256, 2) void conv_mfma(
        const unsigned short* __restrict__ nhwc,   // [b][h][w][ci] bf16
        const unsigned short* __restrict__ wt,     // [tap][co][ci] bf16
        float* __restrict__ out) {
    __shared__ short Hs[HROW * HPIX * CPAD];  // 48960 B halo
    __shared__ short Ws[2][COUT * CIN];       // 2 x 16384 B weight slices

    const int w0 = blockIdx.x * 32;
    const int h0 = blockIdx.y * 8;
    const int b  = blockIdx.z;
    const int tid = threadIdx.x;
    const int lane = tid & 63, wave = tid >> 6;
    const int wm = wave & 1, wn = wave >> 1;
    const int col = lane & 15, quad = lane >> 4;

    // ---- issue async weight stage for tap 0 into buf 0
    {
        const char* src = (const char*)wt;
        char* dst = (char*)&Ws[0][0];
#pragma unroll
        for (int i = 0; i < 4; i++) {
            const int c = wave * 4 + i;
            async16(src + c * 1024 + lane * 16, dst + c * 1024 + lane * 16);
        }
    }

    // ---- stage halo: 10 rows x 34 pixels x 128B = 2720 16B-chunks
    {
        const unsigned short* base = nhwc + ((size_t)b * HIN) * (WIN * CIN);
#pragma unroll
        for (int i = 0; i < 11; i++) {
            const int idx = tid + i * 256;
            if (idx < HROW * HPIX * 8) {
                const int c = idx & 7;
                const int pixel = idx >> 3;
                const int r = pixel / HPIX;
                const int p = pixel - r * HPIX;
                int h = h0 + r; if (h > HIN - 1) h = HIN - 1; // clamp (masked outs)
                bf16x8 v = *(const bf16x8*)(base + ((size_t)h * WIN + w0 + p) * CIN + c * 8);
                *(bf16x8*)&Hs[(r * HPIX + p) * CPAD + c * 8] = v;
            }
        }
    }
    __syncthreads(); // drains async tap-0 weights + halo writes

    // per-wave fragment offsets (shorts)
    int aoff[4], boff[8];
#pragma unroll
    for (int mi = 0; mi < 4; mi++)
        aoff[mi] = (wm * 64 + mi * 16 + col) * CIN + quad * 8;
#pragma unroll
    for (int ni = 0; ni < 8; ni++) {
        const int dy = wn * 4 + (ni >> 1);
        const int dx = (ni & 1) * 16 + col;
        boff[ni] = (dy * HPIX + dx) * CPAD + quad * 8;
    }

    f32x4 acc[4][8] = {};

    for (int t = 0; t < 9; t++) {
        // prefetch next tap's weights into the other buffer (async)
        if (t < 8) {
            const char* src = (const char*)wt + (size_t)(t + 1) * 16384;
            char* dst = (char*)&Ws[(t + 1) & 1][0];
#pragma unroll
            for (int i = 0; i < 4; i++) {
                const int c = wave * 4 + i;
                async16(src + c * 1024 + lane * 16, dst + c * 1024 + lane * 16);
            }
        }

        const int kh = (t * 11) >> 5;        // t/3 for t<9
        const int kw = t - kh * 3;
        const int hshift = (kh * HPIX + kw) * CPAD;
        const short* wsb = &Ws[t & 1][0];

#pragma unroll
        for (int kk = 0; kk < 2; kk++) {
            const int k0 = kk * 32;
            bf16x8 a[4], bb[8];
#pragma unroll
            for (int mi = 0; mi < 4; mi++)
                a[mi] = *(const bf16x8*)&wsb[aoff[mi] + k0];
#pragma unroll
            for (int ni = 0; ni < 8; ni++)
                bb[ni] = *(const bf16x8*)&Hs[boff[ni] + hshift + k0];
#pragma unroll
            for (int mi = 0; mi < 4; mi++)
#pragma unroll
                for (int ni = 0; ni < 8; ni++)
                    acc[mi][ni] = __builtin_amdgcn_mfma_f32_16x16x32_bf16(
                        a[mi], bb[ni], acc[mi][ni], 0, 0, 0);
        }
        __syncthreads(); // all waves done reading Ws[t&1]; drains prefetch
    }

    // ---- epilogue. C/D: col(spatial)=lane&15, row(co)=quad*4+reg.
#pragma unroll
    for (int ni = 0; ni < 8; ni++) {
        const int oh = h0 + wn * 4 + (ni >> 1);
        const int ow = w0 + (ni & 1) * 16 + col;
        if (oh < HO && ow < WO) {
#pragma unroll
            for (int mi = 0; mi < 4; mi++) {
                const int co = wm * 64 + mi * 16 + quad * 4;
                float* o = out + (((size_t)b * COUT + co) * HO + oh) * WO + ow;
#pragma unroll
                for (int r = 0; r < 4; r++)
                    o[(size_t)r * HO * WO] = acc[mi][ni][r];
            }
        }
    }
}

// ---------- Fallback: direct fp32 conv (if d_ws too small) ----------
__global__ __launch_bounds__(256) void conv_direct(
        const float* __restrict__ x, const float* __restrict__ w,
        float* __restrict__ y) {
    const int idx = blockIdx.x * 256 + threadIdx.x;
    if (idx >= BATCH * COUT * HO * WO) return;
    const int ow = idx % WO;
    int t = idx / WO;
    const int oh = t % HO; t /= HO;
    const int co = t % COUT;
    const int b  = t / COUT;
    float acc = 0.f;
    const float* xb = x + (((size_t)b * CIN) * HIN + oh) * WIN + ow;
    const float* wc = w + (size_t)co * (CIN * 9);
    for (int ci = 0; ci < CIN; ci++) {
#pragma unroll
        for (int kh = 0; kh < 3; kh++)
#pragma unroll
            for (int kw = 0; kw < 3; kw++)
                acc += xb[(size_t)ci * (HIN * WIN) + kh * WIN + kw] * wc[ci * 9 + kh * 3 + kw];
    }
    y[idx] = acc;
}

extern "C" void kernel_launch(void* const* d_in, const int* in_sizes, int n_in,
                              void* d_out, int out_size, void* d_ws, size_t ws_size,
                              hipStream_t stream) {
    const float* data    = (const float*)d_in[0];
    const float* weights = (const float*)d_in[1];
    float* out = (float*)d_out;

    const size_t nhwc_bytes = (size_t)BATCH * HIN * WIN * CIN * 2; // 32 MiB
    const size_t slack = 4096;                                     // halo overflow pad
    const size_t wt_bytes = (size_t)9 * COUT * CIN * 2;            // 144 KiB
    const size_t need = nhwc_bytes + slack + wt_bytes;

    if (ws_size >= need) {
        unsigned short* nhwc = (unsigned short*)d_ws;
        unsigned short* wt   = (unsigned short*)((char*)d_ws + nhwc_bytes + slack);
        t1_nchw_to_nhwc<<<dim3(HIN, BATCH), 256, 0, stream>>>(data, nhwc);
        t2_weights<<<(COUT * CIN * 9 + 255) / 256, 256, 0, stream>>>(weights, wt);
        conv_mfma<<<dim3(4, 16, BATCH), 256, 0, stream>>>(nhwc, wt, out);
    } else {
        const int n = BATCH * COUT * HO * WO;
        conv_direct<<<(n + 255) / 256, 256, 0, stream>>>(data, weights, out);
    }
}